// Round 1
// baseline (231.052 us; speedup 1.0000x reference)
//
#include <hip/hip_runtime.h>
#include <hip/hip_bf16.h>
#include <cstdint>
#include <cstddef>

// JacobiKANLinear: DEGREE=5, A=B=1.0. Inputs fp32, output fp32 (HW-verified r1/r2/r5).
#define BATCH   8192
#define IN_F    1024
#define OUT_F   1024
#define KAUG    (6 * 1024)   // slab 0 = silu(x); slab j (1..5) = P_j(tanh x); P0 folded into bias

typedef __bf16 bf16x8 __attribute__((ext_vector_type(8)));
typedef float  f32x4  __attribute__((ext_vector_type(4)));

// Workspace layout (bytes), ~113.3 MB (proven available r5-r8):
static constexpr size_t WAUG_B    = (size_t)OUT_F * KAUG * 2;        // 12,582,912
static constexpr size_t BIAS2_OFF = WAUG_B;                          // 4 KB f32
static constexpr size_t AAUG_OFF  = WAUG_B + 4096;
static constexpr size_t AAUG_B    = (size_t)BATCH * KAUG * 2;        // 100,663,296
static constexpr size_t MMAP_OFF  = AAUG_OFF + AAUG_B;
static constexpr size_t NMAP_OFF  = MMAP_OFF + 1024;

// Jacobi recurrence for A=B=1 (beta_n = 0): P_k = (a_k t)P_{k-1} - (b_k)P_{k-2}
__device__ __constant__ float JAC_A[4] = {64.f/120.f, 180.f/336.f, 384.f/720.f, 700.f/1320.f};
__device__ __constant__ float JAC_B[4] = {48.f/120.f, 144.f/336.f, 320.f/720.f, 600.f/1320.f};

__device__ __forceinline__ unsigned short f2bf(float f)
{
    __hip_bfloat16 h = __float2bfloat16(f);
    return *(unsigned short*)&h;
}
__device__ __forceinline__ unsigned pack2(float lo, float hi)
{
    return (unsigned)f2bf(lo) | ((unsigned)f2bf(hi) << 16);
}
__device__ __forceinline__ float fast_tanh(float x)
{
    const float xc = fminf(fmaxf(x, -15.f), 15.f);
    const float e  = __expf(2.f * xc);
    return (e - 1.f) / (e + 1.f);
}

// ---------------- MFMA C/D layout probe (feeds epilogue) ----------------
__global__ void probe_layout(int* __restrict__ mmap, int* __restrict__ nmap)
{
    __shared__ __align__(16) __hip_bfloat16 A1[16 * 32], B1[16 * 32];
    __shared__ __align__(16) __hip_bfloat16 A2[16 * 32], B2[16 * 32];
    const int lane = threadIdx.x;
    for (int e = lane; e < 512; e += 64) {
        const int m = e >> 5, k = e & 31;
        A1[e] = __float2bfloat16((k == 0) ? (float)(m + 1) : 0.f);
        B1[e] = __float2bfloat16((k == 0) ? 1.f : 0.f);
        A2[e] = __float2bfloat16((k == 0) ? 1.f : 0.f);
        B2[e] = __float2bfloat16((k == 0) ? (float)(m + 1) : 0.f);
    }
    __syncthreads();
    const int quad = lane >> 4, mr = lane & 15;
    const int fi = mr * 4 + quad;
    f32x4 z = {};
    f32x4 d1 = __builtin_amdgcn_mfma_f32_16x16x32_bf16(((const bf16x8*)A1)[fi], ((const bf16x8*)B1)[fi], z, 0, 0, 0);
    f32x4 d2 = __builtin_amdgcn_mfma_f32_16x16x32_bf16(((const bf16x8*)A2)[fi], ((const bf16x8*)B2)[fi], z, 0, 0, 0);
#pragma unroll
    for (int r = 0; r < 4; ++r) {
        mmap[lane * 4 + r] = (int)(d1[r] + 0.5f) - 1;
        nmap[lane * 4 + r] = (int)(d2[r] + 0.5f) - 1;
    }
}

// ---------------- fused prep: blocks [0,1024) = weights+bias; [1024,5120) = acts ----
__global__ void prep_all(const float* __restrict__ X,
                         const float* __restrict__ W,
                         const float* __restrict__ C,
                         const float* __restrict__ bias,
                         __hip_bfloat16* __restrict__ Aaug,
                         __hip_bfloat16* __restrict__ Waug,
                         float* __restrict__ bias2)
{
    const int bid = blockIdx.x;
    const int tid = threadIdx.x;
    if (bid < OUT_F) {
        // --- weights + bias fold for output row o ---
        const int o = bid;
        const int i = tid * 4;
        const size_t wbase = (size_t)o * KAUG;

        const float4 wv = *(const float4*)(W + (size_t)o * IN_F + i);
        ((uint2*)&Waug[wbase + i])[0] = make_uint2(pack2(wv.x, wv.y), pack2(wv.z, wv.w));

        float f[24];   // 24 consecutive floats = C[o][i..i+3][0..5]
        const float2* cp = (const float2*)(C + ((size_t)o * IN_F + i) * 6);
#pragma unroll
        for (int q = 0; q < 12; ++q) { const float2 v = cp[q]; f[q * 2] = v.x; f[q * 2 + 1] = v.y; }
#pragma unroll
        for (int j = 1; j <= 5; ++j) {
            ((uint2*)&Waug[wbase + (size_t)j * IN_F + i])[0] =
                make_uint2(pack2(f[0 + j], f[6 + j]), pack2(f[12 + j], f[18 + j]));
        }
        float s = f[0] + f[6] + f[12] + f[18];        // j=0 terms
#pragma unroll
        for (int off = 32; off > 0; off >>= 1) s += __shfl_down(s, off, 64);
        __shared__ float red[4];
        if ((tid & 63) == 0) red[tid >> 6] = s;
        __syncthreads();
        if (tid == 0) bias2[o] = bias[o] + red[0] + red[1] + red[2] + red[3];
    } else {
        // --- activations: 8 elems/thread, 16B stores ---
        const int gid = (bid - OUT_F) * 256 + tid;
        const int b   = gid >> 7;
        const int i8  = (gid & 127) * 8;
        const float4 x0 = *(const float4*)(X + (size_t)b * IN_F + i8);
        const float4 x1 = *(const float4*)(X + (size_t)b * IN_F + i8 + 4);
        const float sx[8] = {x0.x, x0.y, x0.z, x0.w, x1.x, x1.y, x1.z, x1.w};
        const size_t base = (size_t)b * KAUG + i8;

        float sil[8], t[8], pm1[8], pm2[8];
#pragma unroll
        for (int e = 0; e < 8; ++e) {
            sil[e] = sx[e] / (1.f + __expf(-sx[e]));
            t[e]   = fast_tanh(sx[e]);
            pm2[e] = 1.f; pm1[e] = 2.f * t[e];
        }
        *(uint4*)&Aaug[base] = make_uint4(pack2(sil[0], sil[1]), pack2(sil[2], sil[3]),
                                          pack2(sil[4], sil[5]), pack2(sil[6], sil[7]));
        *(uint4*)&Aaug[base + IN_F] = make_uint4(pack2(pm1[0], pm1[1]), pack2(pm1[2], pm1[3]),
                                                 pack2(pm1[4], pm1[5]), pack2(pm1[6], pm1[7]));
#pragma unroll
        for (int k = 2; k <= 5; ++k) {
#pragma unroll
            for (int e = 0; e < 8; ++e) {
                const float pk = JAC_A[k - 2] * t[e] * pm1[e] - JAC_B[k - 2] * pm2[e];
                pm2[e] = pm1[e]; pm1[e] = pk;
            }
            *(uint4*)&Aaug[base + (size_t)k * IN_F] =
                make_uint4(pack2(pm1[0], pm1[1]), pack2(pm1[2], pm1[3]),
                           pack2(pm1[4], pm1[5]), pack2(pm1[6], pm1[7]));
        }
    }
}

// ---------------- GEMM v2: T1+T2+T3+T4+T5 bundle ----------------
// BM=256, BN=128, BK=64. 512 threads = 8 waves (4M x 2N), per-wave 64x64
// output (acc[4][4], same verified fragment/epilogue structure as v1).
// Grid 32x8 = 256 WGs = exactly 1/CU; XCD = bx%8 so all 8 N-tiles of an
// A-panel share one XCD's L2 (T1).
// Pipeline: TRIPLE-buffered LDS (3 x 48 KB = 144 KB dynamic), prefetch
// distance 2 K-tiles, counted s_waitcnt vmcnt(6) at K-tile boundaries only
// (never 0 in steady state) + raw s_barrier (T3+T4). 4 quadrant-phases per
// K-tile: {8 ds_read_b128 || stage slice -> barrier -> lgkmcnt(0) ->
// setprio(1) -> 8 MFMA -> setprio(0) -> barrier} (T5).
// LDS rows are 128 B (8 x 16B chunks); chunk stored at c ^ (row&7) via
// pre-swizzled GLOBAL source (linear LDS dest, rule #21) -> ds_read_b128
// spreads all 8 chunk-slots uniformly across the wave = conflict-free (T2).
// Soundness of counted vmcnt: every wave issues the identical 6-load
// sequence per tile, so own-wave vmcnt(6) + s_barrier ==> all waves' loads
// for the next tile have landed. Stage of tile t+2 targets buffer (t+2)%3
// = tile t-1's buffer, whose reads were consumed (lgkmcnt(0)) before the
// boundary barrier that precedes these issues -> no clobber race.
__device__ __forceinline__ void async_load16(const void* g, void* l)
{
    __builtin_amdgcn_global_load_lds(
        (const __attribute__((address_space(1))) void*)g,
        (__attribute__((address_space(3))) void*)l,
        16, 0, 0);
}

#define ABYTES 32768          // A region bytes per buffer (256 x 64 x bf16)
#define TILEB  49152          // per-buffer bytes (A 32K + B 16K)
#define NT     96             // K-tiles (6144 / 64)

__global__ __launch_bounds__(512, 2)
void gemm_kan(const __hip_bfloat16* __restrict__ Aaug,
              const __hip_bfloat16* __restrict__ Waug,
              const float* __restrict__ bias2,
              const int* __restrict__ mmap,
              const int* __restrict__ nmap,
              float* __restrict__ out)
{
    extern __shared__ __align__(16) char smem[];   // 3 * 49152 = 147456 B

    const int tid  = threadIdx.x;
    const int lane = tid & 63;
    const int wave = tid >> 6;
    const int wm = wave >> 1, wn = wave & 1;       // 4 M-groups x 2 N-groups
    const int mBase = blockIdx.x * 256;            // M fastest -> XCD = bx % 8
    const int nBase = blockIdx.y * 128;

    // ---- staging maps: linear LDS dest, inverse-swizzled global source ----
    // chunk idx = (j*8+wave)*64 + lane ; row = idx>>3 ; stored chunk = idx&7
    // global k-chunk gc = (idx&7) ^ (row&7)
    const __hip_bfloat16* gA[4]; int lA[4];
#pragma unroll
    for (int j = 0; j < 4; ++j) {
        const int idx = (j * 8 + wave) * 64 + lane;
        const int row = idx >> 3, sc = idx & 7, gc = sc ^ (row & 7);
        gA[j] = Aaug + (size_t)(mBase + row) * KAUG + gc * 8;
        lA[j] = (j * 8 + wave) * 1024;
    }
    const __hip_bfloat16* gB[2]; int lB[2];
#pragma unroll
    for (int j = 0; j < 2; ++j) {
        const int idx = (j * 8 + wave) * 64 + lane;
        const int row = idx >> 3, sc = idx & 7, gc = sc ^ (row & 7);
        gB[j] = Waug + (size_t)(nBase + row) * KAUG + gc * 8;
        lB[j] = ABYTES + (j * 8 + wave) * 1024;
    }

    // ---- fragment read offsets (row&7 == mr&7 since bases are %8==0) ----
    const int quad = lane >> 4, mr = lane & 15;
    int rA[4], rB[4], csw[2];
#pragma unroll
    for (int t = 0; t < 4; ++t) rA[t] = (wm * 64 + t * 16 + mr) * 128;
#pragma unroll
    for (int t = 0; t < 4; ++t) rB[t] = ABYTES + (wn * 64 + t * 16 + mr) * 128;
    csw[0] = ((0 + quad) ^ (mr & 7)) * 16;
    csw[1] = ((4 + quad) ^ (mr & 7)) * 16;

    f32x4 acc[4][4] = {};

    // ---- prologue: tile0 -> buf0, tile1 -> buf1; wait all but newest 6 ----
#pragma unroll
    for (int j = 0; j < 4; ++j) async_load16(gA[j], smem + lA[j]);
#pragma unroll
    for (int j = 0; j < 2; ++j) async_load16(gB[j], smem + lB[j]);
#pragma unroll
    for (int j = 0; j < 4; ++j) async_load16(gA[j] + 64, smem + TILEB + lA[j]);
#pragma unroll
    for (int j = 0; j < 2; ++j) async_load16(gB[j] + 64, smem + TILEB + lB[j]);
    asm volatile("s_waitcnt vmcnt(6)" ::: "memory");
    __builtin_amdgcn_s_barrier();

#define KTILE(CB, SB, KK, DOST)                                              \
    {                                                                        \
        _Pragma("unroll")                                                    \
        for (int ph = 0; ph < 4; ++ph) {                                     \
            const int mh = ph >> 1, nh = ph & 1;                             \
            bf16x8 fa[2][2], fb[2][2];                                       \
            _Pragma("unroll")                                                \
            for (int tf = 0; tf < 2; ++tf) {                                 \
                _Pragma("unroll")                                            \
                for (int ks = 0; ks < 2; ++ks) {                             \
                    fa[tf][ks] = *(const bf16x8*)((CB) + rA[mh * 2 + tf] + csw[ks]); \
                    fb[tf][ks] = *(const bf16x8*)((CB) + rB[nh * 2 + tf] + csw[ks]); \
                }                                                            \
            }                                                                \
            if (DOST) {                                                      \
                if (ph == 0) { async_load16(gA[0] + (KK), (SB) + lA[0]);     \
                               async_load16(gA[1] + (KK), (SB) + lA[1]); }   \
                if (ph == 1) { async_load16(gA[2] + (KK), (SB) + lA[2]);     \
                               async_load16(gA[3] + (KK), (SB) + lA[3]); }   \
                if (ph == 2) { async_load16(gB[0] + (KK), (SB) + lB[0]); }   \
                if (ph == 3) { async_load16(gB[1] + (KK), (SB) + lB[1]); }   \
            }                                                                \
            __builtin_amdgcn_s_barrier();                                    \
            asm volatile("s_waitcnt lgkmcnt(0)" ::: "memory");               \
            __builtin_amdgcn_s_setprio(1);                                   \
            _Pragma("unroll")                                                \
            for (int tm = 0; tm < 2; ++tm) {                                 \
                _Pragma("unroll")                                            \
                for (int tn = 0; tn < 2; ++tn) {                             \
                    _Pragma("unroll")                                        \
                    for (int ks = 0; ks < 2; ++ks)                           \
                        acc[mh * 2 + tm][nh * 2 + tn] =                      \
                            __builtin_amdgcn_mfma_f32_16x16x32_bf16(         \
                                fa[tm][ks], fb[tn][ks],                      \
                                acc[mh * 2 + tm][nh * 2 + tn], 0, 0, 0);     \
                }                                                            \
            }                                                                \
            __builtin_amdgcn_s_setprio(0);                                   \
            if (ph < 3) __builtin_amdgcn_s_barrier();                        \
        }                                                                    \
    }

    int buf = 0, nb = 2;        // compute buffer t%3 ; stage buffer (t+2)%3
    size_t kk = 128;            // element k-offset of tile t+2
#pragma unroll 1
    for (int t = 0; t < NT - 2; ++t) {
        const char* Cb = smem + buf * TILEB;
        char*       Sb = smem + nb  * TILEB;
        KTILE(Cb, Sb, kk, 1);
        // boundary: allow the 6 loads of tile t+2 (just issued) to stay in
        // flight; force tile t+1's 6 (issued last iter) to have landed.
        asm volatile("s_waitcnt vmcnt(6)" ::: "memory");
        __builtin_amdgcn_s_barrier();
        buf = (buf == 2) ? 0 : buf + 1;
        nb  = (nb  == 2) ? 0 : nb  + 1;
        kk += 64;
    }
    {   // t = NT-2: nothing left to stage; drain for the final tile
        const char* Cb = smem + buf * TILEB;
        KTILE(Cb, (char*)nullptr, 0, 0);
        asm volatile("s_waitcnt vmcnt(0)" ::: "memory");
        __builtin_amdgcn_s_barrier();
        buf = (buf == 2) ? 0 : buf + 1;
    }
    {   // t = NT-1
        const char* Cb = smem + buf * TILEB;
        KTILE(Cb, (char*)nullptr, 0, 0);
    }
#undef KTILE

    // ---- direct-store epilogue via measured C/D maps ----
    const int4 mv = ((const int4*)mmap)[lane];
    const int4 nv = ((const int4*)nmap)[lane];
    const int mm[4] = {mv.x, mv.y, mv.z, mv.w};
    const int nn[4] = {nv.x, nv.y, nv.z, nv.w};
#pragma unroll
    for (int i = 0; i < 4; ++i) {
#pragma unroll
        for (int jj = 0; jj < 4; ++jj) {
#pragma unroll
            for (int r = 0; r < 4; ++r) {
                const int row = mBase + wm * 64 + i * 16 + mm[r];
                const int col = nBase + wn * 64 + jj * 16 + nn[r];
                out[(size_t)row * OUT_F + col] = acc[i][jj][r] + bias2[col];
            }
        }
    }
}

// ---------------- launch ----------------

extern "C" void kernel_launch(void* const* d_in, const int* in_sizes, int n_in,
                              void* d_out, int out_size, void* d_ws, size_t ws_size,
                              hipStream_t stream)
{
    (void)out_size; (void)ws_size;
    const float* x    = (const float*)d_in[0];
    const float* W    = (const float*)d_in[1];
    const float* C    = (const float*)d_in[2];
    const float* bias = (const float*)d_in[3];
    for (int i = 0; i < n_in; ++i) {
        if      (in_sizes[i] == BATCH * IN_F)     x    = (const float*)d_in[i];
        else if (in_sizes[i] == OUT_F * IN_F)     W    = (const float*)d_in[i];
        else if (in_sizes[i] == OUT_F * IN_F * 6) C    = (const float*)d_in[i];
        else if (in_sizes[i] == OUT_F)            bias = (const float*)d_in[i];
    }
    float* out = (float*)d_out;
    char* ws = (char*)d_ws;
    __hip_bfloat16* Waug  = (__hip_bfloat16*)ws;
    float*          bias2 = (float*)(ws + BIAS2_OFF);
    __hip_bfloat16* Aaug  = (__hip_bfloat16*)(ws + AAUG_OFF);
    int*            mmap  = (int*)(ws + MMAP_OFF);
    int*            nmap  = (int*)(ws + NMAP_OFF);

    // 144 KB dynamic LDS (> default 64 KB): opt in once (HK-proven path on
    // gfx950; LDS/CU = 160 KB). Host-side, non-stream call: graph-capture safe.
    static bool smem_attr_done = false;
    if (!smem_attr_done) {
        (void)hipFuncSetAttribute((const void*)gemm_kan,
                                  hipFuncAttributeMaxDynamicSharedMemorySize,
                                  3 * TILEB);
        smem_attr_done = true;
    }

    probe_layout<<<dim3(1), dim3(64), 0, stream>>>(mmap, nmap);
    prep_all<<<dim3(OUT_F + (BATCH * IN_F) / 2048), dim3(256), 0, stream>>>(
        x, W, C, bias, Aaug, Waug, bias2);
    gemm_kan<<<dim3(BATCH / 256, OUT_F / 128), dim3(512), 3 * TILEB, stream>>>(
        Aaug, Waug, bias2, mmap, nmap, out);
}